// Round 9
// baseline (239.420 us; speedup 1.0000x reference)
//
#include <hip/hip_runtime.h>
#include <hip/hip_bf16.h>
#include <hip/hip_fp16.h>

typedef _Float16 f16;
typedef _Float16 f16x8 __attribute__((ext_vector_type(8)));
typedef _Float16 f16x4 __attribute__((ext_vector_type(4)));
typedef float f32x4 __attribute__((ext_vector_type(4)));

// Problem constants
constexpr int B = 4;
constexpr int T = 4096;
constexpr int C = 768;
constexpr int NH = 12;
constexpr int DH = 64;
constexpr int E = 4;
constexpr int SPAN = 64;
constexpr int N = T / SPAN;
constexpr int BN = B * N;       // 256 spans
constexpr int GH = 128;
constexpr int BTC = B * T * C;  // 12,582,912

// f16x8 unit counts for the W converter
constexpr int U_WE = E * C * C / 8;        //   294,912 (per expert weight tensor)
constexpr int U_WO = C * C / 8;            //    73,728
constexpr int U_WTOT = 3 * U_WE + U_WO;

// lgkm-only barrier: no vmcnt drain (in-flight global loads stay in flight)
#define LGKM_BARRIER()                                      \
    do {                                                    \
        asm volatile("s_waitcnt lgkmcnt(0)" ::: "memory");  \
        __builtin_amdgcn_s_barrier();                       \
        __builtin_amdgcn_sched_barrier(0);                  \
    } while (0)

// ---------------------------------------------------------------------------
// x f32->f16 conversion fused with per-span mean pooling.
// v10: x16 is written in MFMA A-FRAGMENT layout:
//   unit index = span*6144 + (kt*4 + m)*64 + lg*16 + lr
//   (kt = k/32, lg = (k%32)/8, m = row/16, lr = row%16)
// so qkv can load A-fragments directly from global, coalesced.
// ---------------------------------------------------------------------------
__global__ __launch_bounds__(768) void cvt_x_pool(
    const float* __restrict__ x, f16* __restrict__ x16,
    float* __restrict__ pooled) {
    int span = blockIdx.x;
    int tid = threadIdx.x;
    int u = tid % 96, rg = tid / 96;     // rg 0..7
    __shared__ float part[8][C];         // 24 KB

    const float* xb = x + (size_t)span * SPAN * C;
    f16x8* xo = (f16x8*)x16 + (size_t)span * 6144;
    int kt = u >> 2, lg = u & 3;
    float a8[8] = {};
    #pragma unroll
    for (int j = 0; j < 8; ++j) {
        int r = rg * 8 + j;
        const float4* s = (const float4*)(xb + (size_t)r * C + u * 8);
        float4 A = s[0], Bv = s[1];
        f16x8 o;
        o[0] = (f16)A.x;  o[1] = (f16)A.y;  o[2] = (f16)A.z;  o[3] = (f16)A.w;
        o[4] = (f16)Bv.x; o[5] = (f16)Bv.y; o[6] = (f16)Bv.z; o[7] = (f16)Bv.w;
        int m = r >> 4, lr = r & 15;
        xo[(kt * 4 + m) * 64 + lg * 16 + lr] = o;
        a8[0] += A.x;  a8[1] += A.y;  a8[2] += A.z;  a8[3] += A.w;
        a8[4] += Bv.x; a8[5] += Bv.y; a8[6] += Bv.z; a8[7] += Bv.w;
    }
    #pragma unroll
    for (int j = 0; j < 8; ++j) part[rg][u * 8 + j] = a8[j];
    __syncthreads();
    float s = 0.f;
    #pragma unroll
    for (int g = 0; g < 8; ++g) s += part[g][tid];
    pooled[(size_t)span * C + tid] = s * (1.f / 64.f);
}

// ---------------------------------------------------------------------------
// W f32 -> f16 conversion.
// v10: Wq/Wk/Wv are written in MFMA B-FRAGMENT layout:
//   unit index = (e*12 + cb)*6144 + (kt*4 + n)*64 + lg*16 + lr
//   (cb = orow/64, n = (orow%64)/16, lr = orow%16; kt = k/32, lg = (k%32)/8)
// Wo stays row-major (outproj stages it via LDS as before).
// ---------------------------------------------------------------------------
__global__ void cvt_w(const float* __restrict__ Wq, const float* __restrict__ Wk,
                      const float* __restrict__ Wv, const float* __restrict__ Wo,
                      f16* __restrict__ Wq16, f16* __restrict__ Wk16,
                      f16* __restrict__ Wv16, f16* __restrict__ Wo16) {
    int i = blockIdx.x * blockDim.x + threadIdx.x;
    int stride = gridDim.x * blockDim.x;
    for (; i < U_WTOT; i += stride) {
        const float* src; f16* dst; int u;
        bool frag = true;
        if (i < U_WE)               { src = Wq; dst = Wq16; u = i; }
        else if (i < 2 * U_WE)      { src = Wk; dst = Wk16; u = i - U_WE; }
        else if (i < 3 * U_WE)      { src = Wv; dst = Wv16; u = i - 2 * U_WE; }
        else                        { src = Wo; dst = Wo16; u = i - 3 * U_WE; frag = false; }
        float4 a = ((const float4*)src)[2 * u];
        float4 b = ((const float4*)src)[2 * u + 1];
        f16x8 o;
        o[0] = (f16)a.x; o[1] = (f16)a.y; o[2] = (f16)a.z; o[3] = (f16)a.w;
        o[4] = (f16)b.x; o[5] = (f16)b.y; o[6] = (f16)b.z; o[7] = (f16)b.w;
        if (frag) {
            int e   = u / (C * C / 8);
            int rem = u - e * (C * C / 8);
            int orow = rem / 96;           // W output row (= output col of proj)
            int ku   = rem - orow * 96;    // 8-elem k unit
            int cb = orow >> 6, nn = (orow >> 4) & 3, lr = orow & 15;
            int kt = ku >> 2, lg = ku & 3;
            ((f16x8*)dst)[(size_t)(e * 12 + cb) * 6144 + (kt * 4 + nn) * 64 + lg * 16 + lr] = o;
        } else {
            ((f16x8*)dst)[u] = o;
        }
    }
}

// ---------------------------------------------------------------------------
// Gating MLP on precomputed pooled means. One block per span, 128 threads.
// ---------------------------------------------------------------------------
__global__ __launch_bounds__(128) void gate_mlp(
    const float* __restrict__ pooled,
    const float* __restrict__ gW1, const float* __restrict__ gb1,
    const float* __restrict__ gW2, const float* __restrict__ gb2,
    int* __restrict__ eidx, float* __restrict__ ewts,
    float* __restrict__ ent_partial) {
    int span = blockIdx.x;
    int tid = threadIdx.x;
    __shared__ float pl[C];
    __shared__ float h[GH];
    __shared__ float logits[E];

    for (int c = tid; c < C; c += 128) pl[c] = pooled[(size_t)span * C + c];
    __syncthreads();

    {
        float acc = gb1[tid];
        const float* wrow = gW1 + (size_t)tid * C;
        #pragma unroll 8
        for (int c = 0; c < C; ++c) acc += pl[c] * wrow[c];
        h[tid] = acc > 0.f ? acc : 0.f;
    }
    __syncthreads();

    if (tid < E) {
        float acc = gb2[tid];
        const float* wrow = gW2 + (size_t)tid * GH;
        #pragma unroll 8
        for (int j = 0; j < GH; ++j) acc += h[j] * wrow[j];
        logits[tid] = acc;
    }
    __syncthreads();

    if (tid == 0) {
        int i0 = 0; float v0 = logits[0];
        for (int e = 1; e < E; ++e) { if (logits[e] > v0) { v0 = logits[e]; i0 = e; } }
        int i1 = -1; float v1 = -3.0e38f;
        for (int e = 0; e < E; ++e) { if (e != i0 && logits[e] > v1) { v1 = logits[e]; i1 = e; } }
        float bq_ = expf(v1 - v0);
        float s = 1.f + bq_;
        float sm0 = 1.f / s;
        float sm1 = bq_ / s;
        eidx[span * 2 + 0] = i0;
        eidx[span * 2 + 1] = i1;
        ewts[span * 2 + 0] = sm0;
        ewts[span * 2 + 1] = sm1;
        float p0 = fmaxf(sm0, 1e-9f), p1 = fmaxf(sm1, 1e-9f);
        ent_partial[span] = sm0 * logf(p0) + sm1 * logf(p1);
    }
}

__global__ void entropy_kernel(const float* __restrict__ ent_partial, float* __restrict__ out_ent) {
    __shared__ float sh[256];
    int tid = threadIdx.x;
    sh[tid] = ent_partial[tid];
    __syncthreads();
    for (int s = 128; s > 0; s >>= 1) {
        if (tid < s) sh[tid] += sh[tid + s];
        __syncthreads();
    }
    if (tid == 0) *out_ent = -sh[0] * (1.0f / (float)BN);
}

// ---------------------------------------------------------------------------
// QKV v10: PURE STREAMING — no LDS, no barriers.
// x16 and W are pre-fragmentized (cvt kernels), so every wave loads its
// A/B fragments directly from global with perfect coalescing (1 KB/inst),
// combines experts in registers, and feeds MFMA. Waves fully independent;
// 3 waves/SIMD hide load latency under the MFMA pipe (~310 cy/chunk/wave).
// grid (span=256, otile=3, proj=3), 256 threads = 4 waves; wave = 64 rows
// x 64 cols (acc 4x4), cb = otile*4 + wv.
// For proj==V the output is written TRANSPOSED: vt[span][col][t].
// ---------------------------------------------------------------------------
__global__ __launch_bounds__(256, 3) void qkv_mfma(
    const f16* __restrict__ xh,
    const f16* __restrict__ Wq16, const float* __restrict__ bq,
    const f16* __restrict__ Wk16, const float* __restrict__ bk,
    const f16* __restrict__ Wv16, const float* __restrict__ bv,
    const int* __restrict__ eidx, const float* __restrict__ ewts,
    f16* __restrict__ q16, f16* __restrict__ k16, f16* __restrict__ vt)
{
    int span  = blockIdx.x;
    int otile = blockIdx.y;
    int proj  = blockIdx.z;

    const f16* W; const float* bias; f16* out;
    if (proj == 0)      { W = Wq16; bias = bq; out = q16; }
    else if (proj == 1) { W = Wk16; bias = bk; out = k16; }
    else                { W = Wv16; bias = bv; out = vt; }

    int e0 = eidx[span * 2 + 0], e1 = eidx[span * 2 + 1];
    float w0 = ewts[span * 2 + 0], w1 = ewts[span * 2 + 1];
    f16 w0h = (f16)w0, w1h = (f16)w1;

    int tid = threadIdx.x;
    int lane = tid & 63, wv = tid >> 6;
    int lr = lane & 15, lg = lane >> 4;
    int cb = otile * 4 + wv;              // 64-col block this wave owns

    const f16x8* xu  = (const f16x8*)xh + (size_t)span * 6144 + lane;
    const f16x8* wu0 = (const f16x8*)W + ((size_t)e0 * 12 + cb) * 6144 + lane;
    const f16x8* wu1 = (const f16x8*)W + ((size_t)e1 * 12 + cb) * 6144 + lane;

    f32x4 acc[4][4] = {};

    #pragma unroll 4
    for (int kt = 0; kt < 24; ++kt) {
        f16x8 af[4], bf[4];
        #pragma unroll
        for (int m = 0; m < 4; ++m) af[m] = xu[(kt * 4 + m) * 64];
        #pragma unroll
        for (int n = 0; n < 4; ++n) {
            f16x8 b0 = wu0[(kt * 4 + n) * 64];
            f16x8 b1 = wu1[(kt * 4 + n) * 64];
            bf[n] = b0 * w0h + b1 * w1h;
        }
        #pragma unroll
        for (int m = 0; m < 4; ++m)
            #pragma unroll
            for (int n = 0; n < 4; ++n)
                acc[m][n] = __builtin_amdgcn_mfma_f32_16x16x32_f16(af[m], bf[n], acc[m][n], 0, 0, 0);
    }

    if (proj == 2) {
        // transposed store: vt[span][col][t], t packed 4-at-a-time
        f16* vtb = out + (size_t)span * C * 64;
        #pragma unroll
        for (int n = 0; n < 4; ++n) {
            int col = cb * 64 + n * 16 + lr;
            float be = w0 * bias[(size_t)e0 * C + col] + w1 * bias[(size_t)e1 * C + col];
            #pragma unroll
            for (int m = 0; m < 4; ++m) {
                f16x4 pk;
                #pragma unroll
                for (int r = 0; r < 4; ++r) pk[r] = (f16)(acc[m][n][r] + be);
                *(f16x4*)&vtb[(size_t)col * 64 + m * 16 + lg * 4] = pk;
            }
        }
    } else {
        f16* outb = out + (size_t)span * 64 * C;
        #pragma unroll
        for (int n = 0; n < 4; ++n) {
            int col = cb * 64 + n * 16 + lr;
            float be = w0 * bias[(size_t)e0 * C + col] + w1 * bias[(size_t)e1 * C + col];
            #pragma unroll
            for (int m = 0; m < 4; ++m) {
                #pragma unroll
                for (int r = 0; r < 4; ++r) {
                    int row = m * 16 + lg * 4 + r;
                    outb[(size_t)row * C + col] = (f16)(acc[m][n][r] + be);
                }
            }
        }
    }
}

// ---------------------------------------------------------------------------
// MFMA attention. grid (NH, BN), 256 threads = 4 waves; wave mt owns q-rows
// [mt*16, mt*16+16). K and V^T staged in LDS (stride 72 halves = 144 B).
// All barriers lgkm-only (they order only LDS data).
// ---------------------------------------------------------------------------
__global__ __launch_bounds__(256) void attn_mfma(
    const f16* __restrict__ q16, const f16* __restrict__ k16,
    const f16* __restrict__ vt, f16* __restrict__ a16)
{
    int h = blockIdx.x, span = blockIdx.y;
    __shared__ __align__(16) f16 Klds[64 * 72];
    __shared__ __align__(16) f16 Vlds[64 * 72];
    __shared__ __align__(16) f16 Plds[64 * 72];

    int tid = threadIdx.x;
    int lane = tid & 63, mt = tid >> 6;
    int lr = lane & 15, lg = lane >> 4;

    const f16x8* ku = (const f16x8*)k16;
    const f16x8* vu = (const f16x8*)vt;
    #pragma unroll
    for (int i = 0; i < 2; ++i) {
        int id = tid + i * 256;
        int r = id >> 3, u = id & 7;
        *(f16x8*)&Klds[r * 72 + u * 8] = ku[(size_t)span * 6144 + (size_t)r * 96 + h * 8 + u];
        *(f16x8*)&Vlds[r * 72 + u * 8] = vu[(size_t)span * 6144 + (size_t)(h * 64 + r) * 8 + u];
    }
    // q loads issue here; consumed after the barrier (latency overlapped)
    const f16x8* qu = (const f16x8*)q16;
    f16x8 qa[2];
    #pragma unroll
    for (int kk = 0; kk < 2; ++kk)
        qa[kk] = qu[(size_t)span * 6144 + (size_t)(mt * 16 + lr) * 96 + h * 8 + kk * 4 + lg];

    LGKM_BARRIER();

    f32x4 accs[4] = {};
    #pragma unroll
    for (int nt = 0; nt < 4; ++nt) {
        #pragma unroll
        for (int kk = 0; kk < 2; ++kk) {
            f16x8 kb = *(const f16x8*)&Klds[(nt * 16 + lr) * 72 + kk * 32 + lg * 8];
            accs[nt] = __builtin_amdgcn_mfma_f32_16x16x32_f16(qa[kk], kb, accs[nt], 0, 0, 0);
        }
    }

    #pragma unroll
    for (int nt = 0; nt < 4; ++nt) accs[nt] *= 0.125f;
    f32x4 m4;
    #pragma unroll
    for (int r = 0; r < 4; ++r)
        m4[r] = fmaxf(fmaxf(accs[0][r], accs[1][r]), fmaxf(accs[2][r], accs[3][r]));
    #pragma unroll
    for (int st = 1; st < 16; st <<= 1) {
        #pragma unroll
        for (int r = 0; r < 4; ++r) m4[r] = fmaxf(m4[r], __shfl_xor(m4[r], st));
    }
    f32x4 ps[4];
    f32x4 sum4 = {0.f, 0.f, 0.f, 0.f};
    #pragma unroll
    for (int nt = 0; nt < 4; ++nt)
        #pragma unroll
        for (int r = 0; r < 4; ++r) {
            ps[nt][r] = __expf(accs[nt][r] - m4[r]);
            sum4[r] += ps[nt][r];
        }
    #pragma unroll
    for (int st = 1; st < 16; st <<= 1) {
        #pragma unroll
        for (int r = 0; r < 4; ++r) sum4[r] += __shfl_xor(sum4[r], st);
    }
    f32x4 inv4;
    #pragma unroll
    for (int r = 0; r < 4; ++r) inv4[r] = 1.0f / sum4[r];

    #pragma unroll
    for (int nt = 0; nt < 4; ++nt)
        #pragma unroll
        for (int r = 0; r < 4; ++r)
            Plds[(mt * 16 + lg * 4 + r) * 72 + nt * 16 + lr] = (f16)ps[nt][r];

    LGKM_BARRIER();

    f16x8 pa[2];
    #pragma unroll
    for (int kkt = 0; kkt < 2; ++kkt)
        pa[kkt] = *(const f16x8*)&Plds[(mt * 16 + lr) * 72 + kkt * 32 + lg * 8];
    f32x4 acco[4] = {};
    #pragma unroll
    for (int nt = 0; nt < 4; ++nt) {
        #pragma unroll
        for (int kkt = 0; kkt < 2; ++kkt) {
            f16x8 vb = *(const f16x8*)&Vlds[(nt * 16 + lr) * 72 + kkt * 32 + lg * 8];
            acco[nt] = __builtin_amdgcn_mfma_f32_16x16x32_f16(pa[kkt], vb, acco[nt], 0, 0, 0);
        }
    }

    #pragma unroll
    for (int nt = 0; nt < 4; ++nt)
        #pragma unroll
        for (int r = 0; r < 4; ++r)
            Klds[(mt * 16 + lg * 4 + r) * 72 + nt * 16 + lr] = (f16)(acco[nt][r] * inv4[r]);

    LGKM_BARRIER();

    int row = mt * 16 + (lane >> 2);
    int u2 = (lane & 3) * 2;
    f16x8 o0 = *(const f16x8*)&Klds[row * 72 + u2 * 8];
    f16x8 o1 = *(const f16x8*)&Klds[row * 72 + u2 * 8 + 8];
    f16x8* au = (f16x8*)a16;
    au[(size_t)span * 6144 + (size_t)row * 96 + h * 8 + u2]     = o0;
    au[(size_t)span * 6144 + (size_t)row * 96 + h * 8 + u2 + 1] = o1;
}

// ---------------------------------------------------------------------------
// Output projection via f16 MFMA. grid (rt=128, otile=3), 512 threads (8 waves).
// Register prefetch in flight across lgkm-only barriers.
// ---------------------------------------------------------------------------
__global__ __launch_bounds__(512) void outproj_mfma(
    const f16* __restrict__ ah, const f16* __restrict__ Wo16,
    const float* __restrict__ bo, float* __restrict__ Y)
{
    int rt = blockIdx.x;
    int otile = blockIdx.y;

    __shared__ f16x8 as_u[128 * 8];   // 16 KB
    __shared__ f16x8 ws_u[256 * 8];   // 32 KB

    const f16x8* au  = (const f16x8*)(ah + (size_t)rt * 128 * C);
    const f16x8* Wou = (const f16x8*)(Wo16 + (size_t)otile * 256 * C);

    int tid = threadIdx.x;
    int lane = tid & 63, wv = tid >> 6;
    int lr = lane & 15, lg = lane >> 4;
    int wm = (wv >> 2) * 64;
    int wn = (wv & 3) * 64;

    f32x4 acc[4][4] = {};

    f16x8 ar_[2], wr_[4];
    // prologue: prefetch chunk 0
    #pragma unroll
    for (int i = 0; i < 2; ++i) {
        int id = tid + i * 512;
        ar_[i] = au[(size_t)(id >> 3) * 96 + (id & 7)];
    }
    #pragma unroll
    for (int i = 0; i < 4; ++i) {
        int id = tid + i * 512;
        wr_[i] = Wou[(size_t)(id >> 3) * 96 + (id & 7)];
    }

    for (int kc8 = 0; kc8 < 96; kc8 += 8) {
        // stage current regs -> LDS (swizzled)
        #pragma unroll
        for (int i = 0; i < 2; ++i) {
            int id = tid + i * 512;
            int r = id >> 3, u = id & 7;
            as_u[r * 8 + (u ^ (r & 7))] = ar_[i];
        }
        #pragma unroll
        for (int i = 0; i < 4; ++i) {
            int id = tid + i * 512;
            int r = id >> 3, u = id & 7;
            ws_u[r * 8 + (u ^ (r & 7))] = wr_[i];
        }

        // prefetch next chunk; stays in flight across both barriers
        if (kc8 < 88) {
            int kn = kc8 + 8;
            #pragma unroll
            for (int i = 0; i < 2; ++i) {
                int id = tid + i * 512;
                ar_[i] = au[(size_t)(id >> 3) * 96 + kn + (id & 7)];
            }
            #pragma unroll
            for (int i = 0; i < 4; ++i) {
                int id = tid + i * 512;
                wr_[i] = Wou[(size_t)(id >> 3) * 96 + kn + (id & 7)];
            }
        }

        LGKM_BARRIER();

        #pragma unroll
        for (int kk = 0; kk < 2; ++kk) {
            int ub = kk * 4 + lg;
            f16x8 afrag[4], bfrag[4];
            #pragma unroll
            for (int m = 0; m < 4; ++m) {
                int r = wm + m * 16 + lr;
                afrag[m] = as_u[r * 8 + (ub ^ (r & 7))];
            }
            #pragma unroll
            for (int n = 0; n < 4; ++n) {
                int r = wn + n * 16 + lr;
                bfrag[n] = ws_u[r * 8 + (ub ^ (r & 7))];
            }
            #pragma unroll
            for (int m = 0; m < 4; ++m)
                #pragma unroll
                for (int n = 0; n < 4; ++n)
                    acc[m][n] = __builtin_amdgcn_mfma_f32_16x16x32_f16(afrag[m], bfrag[n], acc[m][n], 0, 0, 0);
        }

        LGKM_BARRIER();
    }

    #pragma unroll
    for (int n = 0; n < 4; ++n) {
        int col = otile * 256 + wn + n * 16 + lr;
        float be = bo[col];
        #pragma unroll
        for (int m = 0; m < 4; ++m) {
            #pragma unroll
            for (int r = 0; r < 4; ++r) {
                int row = rt * 128 + wm + m * 16 + lg * 4 + r;
                Y[(size_t)row * C + col] = acc[m][n][r] + be;
            }
        }
    }
}

// ---------------------------------------------------------------------------
extern "C" void kernel_launch(void* const* d_in, const int* in_sizes, int n_in,
                              void* d_out, int out_size, void* d_ws, size_t ws_size,
                              hipStream_t stream) {
    const float* x   = (const float*)d_in[0];
    const float* Wq  = (const float*)d_in[1];
    const float* bq  = (const float*)d_in[2];
    const float* Wk  = (const float*)d_in[3];
    const float* bk  = (const float*)d_in[4];
    const float* Wv  = (const float*)d_in[5];
    const float* bv  = (const float*)d_in[6];
    const float* gW1 = (const float*)d_in[7];
    const float* gb1 = (const float*)d_in[8];
    const float* gW2 = (const float*)d_in[9];
    const float* gb2 = (const float*)d_in[10];
    const float* Wo  = (const float*)d_in[11];
    const float* bo  = (const float*)d_in[12];

    float* out = (float*)d_out;

    char* ws = (char*)d_ws;
    const size_t h_btc = (size_t)BTC * sizeof(f16);            // 25,165,824
    f16* x16  = (f16*)(ws);
    f16* q16  = (f16*)(ws + 1 * h_btc);
    f16* k16  = (f16*)(ws + 2 * h_btc);
    f16* vt16 = (f16*)(ws + 3 * h_btc);   // transposed V: [span][col][t]
    f16* a16  = (f16*)(ws + 4 * h_btc);
    size_t off = 5 * h_btc;
    const size_t wsz = (size_t)E * C * C * sizeof(f16);        // 4,718,592
    f16* Wq16 = (f16*)(ws + off); off += wsz;
    f16* Wk16 = (f16*)(ws + off); off += wsz;
    f16* Wv16 = (f16*)(ws + off); off += wsz;
    f16* Wo16 = (f16*)(ws + off); off += (size_t)C * C * sizeof(f16);
    int*   eidx = (int*)(ws + off); off += 2048;
    float* ewts = (float*)(ws + off); off += 2048;
    float* entp = (float*)(ws + off); off += 1024;
    float* pooled = (float*)(ws + off); off += (size_t)BN * C * sizeof(float);

    cvt_x_pool<<<dim3(BN), dim3(768), 0, stream>>>(x, x16, pooled);
    cvt_w<<<dim3(1024), dim3(256), 0, stream>>>(Wq, Wk, Wv, Wo,
                                                Wq16, Wk16, Wv16, Wo16);
    gate_mlp<<<dim3(BN), dim3(128), 0, stream>>>(pooled, gW1, gb1, gW2, gb2,
                                                 eidx, ewts, entp);
    entropy_kernel<<<dim3(1), dim3(256), 0, stream>>>(entp, out + BTC);

    qkv_mfma<<<dim3(BN, 3, 3), dim3(256), 0, stream>>>(x16, Wq16, bq, Wk16, bk, Wv16, bv,
                                                       eidx, ewts, q16, k16, vt16);
    attn_mfma<<<dim3(NH, BN), dim3(256), 0, stream>>>(q16, k16, vt16, a16);
    outproj_mfma<<<dim3(128, 3), dim3(512), 0, stream>>>(a16, Wo16, bo, out);
}

// Round 10
// 209.817 us; speedup vs baseline: 1.1411x; 1.1411x over previous
//
#include <hip/hip_runtime.h>
#include <hip/hip_bf16.h>
#include <hip/hip_fp16.h>

typedef _Float16 f16;
typedef _Float16 f16x8 __attribute__((ext_vector_type(8)));
typedef _Float16 f16x4 __attribute__((ext_vector_type(4)));
typedef float f32x4 __attribute__((ext_vector_type(4)));

// Problem constants
constexpr int B = 4;
constexpr int T = 4096;
constexpr int C = 768;
constexpr int NH = 12;
constexpr int DH = 64;
constexpr int E = 4;
constexpr int SPAN = 64;
constexpr int N = T / SPAN;
constexpr int BN = B * N;       // 256 spans
constexpr int GH = 128;
constexpr int BTC = B * T * C;  // 12,582,912

constexpr int U_WO = C * C / 8;            //    73,728

// lgkm-only barrier: no vmcnt drain (in-flight global loads stay in flight)
#define LGKM_BARRIER()                                      \
    do {                                                    \
        asm volatile("s_waitcnt lgkmcnt(0)" ::: "memory");  \
        __builtin_amdgcn_s_barrier();                       \
        __builtin_amdgcn_sched_barrier(0);                  \
    } while (0)

// ---------------------------------------------------------------------------
// x f32->f16 conversion fused with per-span mean pooling.
// v11: coalesced f32 read -> convert (+pool, f32 math identical to ref) ->
// LDS (XOR-swizzled) -> COALESCED fragment-order global write:
//   x16 unit index = span*6144 + (kt*4 + m)*64 + lg*16 + lr
// ---------------------------------------------------------------------------
__global__ __launch_bounds__(768) void cvt_x_pool(
    const float* __restrict__ x, f16* __restrict__ x16,
    float* __restrict__ pooled) {
    int span = blockIdx.x;
    int tid = threadIdx.x;
    int u = tid % 96, rg = tid / 96;     // rg 0..7
    __shared__ f16x8 xlds[6144];         // 96 KB
    __shared__ float part[8][C];         // 24 KB

    const float* xb = x + (size_t)span * SPAN * C;
    float a8[8] = {};
    #pragma unroll
    for (int j = 0; j < 8; ++j) {
        int r = rg * 8 + j;
        const float4* s = (const float4*)(xb + (size_t)r * C + u * 8);
        float4 A = s[0], Bv = s[1];
        f16x8 o;
        o[0] = (f16)A.x;  o[1] = (f16)A.y;  o[2] = (f16)A.z;  o[3] = (f16)A.w;
        o[4] = (f16)Bv.x; o[5] = (f16)Bv.y; o[6] = (f16)Bv.z; o[7] = (f16)Bv.w;
        xlds[r * 96 + (u & ~7) + ((u & 7) ^ (r & 7))] = o;
        a8[0] += A.x;  a8[1] += A.y;  a8[2] += A.z;  a8[3] += A.w;
        a8[4] += Bv.x; a8[5] += Bv.y; a8[6] += Bv.z; a8[7] += Bv.w;
    }
    #pragma unroll
    for (int j = 0; j < 8; ++j) part[rg][u * 8 + j] = a8[j];
    __syncthreads();
    float s = 0.f;
    #pragma unroll
    for (int g = 0; g < 8; ++g) s += part[g][tid];
    pooled[(size_t)span * C + tid] = s * (1.f / 64.f);

    // coalesced fragment-order write: unit = (kt*4+m)*64 + lg*16 + lr
    f16x8* xo = (f16x8*)x16 + (size_t)span * 6144;
    #pragma unroll
    for (int j = 0; j < 8; ++j) {
        int un = tid + j * 768;
        int lr = un & 15, lg = (un >> 4) & 3, m = (un >> 6) & 3, kt = un >> 8;
        int row = m * 16 + lr, ku = kt * 4 + lg;
        xo[un] = xlds[row * 96 + (ku & ~7) + ((ku & 7) ^ (row & 7))];
    }
}

// ---------------------------------------------------------------------------
// Wq/Wk/Wv f32 -> f16 in MFMA B-FRAGMENT layout, coalesced both sides via
// LDS transpose. One block per (tensor, e, cb): 64 output rows x 768 K.
//   dst unit index = (e*12 + cb)*6144 + (kt*4 + n)*64 + lg*16 + lr
// ---------------------------------------------------------------------------
__global__ __launch_bounds__(768) void cvt_w_frag(
    const float* __restrict__ Wq, const float* __restrict__ Wk,
    const float* __restrict__ Wv,
    f16* __restrict__ Wq16, f16* __restrict__ Wk16, f16* __restrict__ Wv16) {
    int slice = blockIdx.x;          // 0..47 = e*12 + cb
    int tsel  = blockIdx.y;          // 0..2
    const float* src; f16* dst;
    if (tsel == 0)      { src = Wq; dst = Wq16; }
    else if (tsel == 1) { src = Wk; dst = Wk16; }
    else                { src = Wv; dst = Wv16; }
    int e = slice / 12, cb = slice % 12;

    __shared__ f16x8 wlds[6144];     // 96 KB
    int tid = threadIdx.x;

    // read: 64 rows x 96 units, coalesced
    const float* wb = src + ((size_t)e * C + cb * 64) * C;
    #pragma unroll
    for (int j = 0; j < 8; ++j) {
        int g = tid + j * 768;
        int row = g / 96, ku = g % 96;
        const float4* sp = (const float4*)(wb + (size_t)row * C + ku * 8);
        float4 A = sp[0], Bv = sp[1];
        f16x8 o;
        o[0] = (f16)A.x;  o[1] = (f16)A.y;  o[2] = (f16)A.z;  o[3] = (f16)A.w;
        o[4] = (f16)Bv.x; o[5] = (f16)Bv.y; o[6] = (f16)Bv.z; o[7] = (f16)Bv.w;
        wlds[row * 96 + (ku & ~7) + ((ku & 7) ^ (row & 7))] = o;
    }
    __syncthreads();

    // write: fragment order, coalesced
    f16x8* wo = (f16x8*)dst + (size_t)slice * 6144;
    #pragma unroll
    for (int j = 0; j < 8; ++j) {
        int un = tid + j * 768;
        int lr = un & 15, lg = (un >> 4) & 3, nn = (un >> 6) & 3, kt = un >> 8;
        int row = nn * 16 + lr, ku = kt * 4 + lg;
        wo[un] = wlds[row * 96 + (ku & ~7) + ((ku & 7) ^ (row & 7))];
    }
}

// ---------------------------------------------------------------------------
// Wo f32 -> f16, row-major (outproj stages via LDS as before).
// ---------------------------------------------------------------------------
__global__ void cvt_wo(const float* __restrict__ Wo, f16* __restrict__ Wo16) {
    int i = blockIdx.x * blockDim.x + threadIdx.x;
    int stride = gridDim.x * blockDim.x;
    for (; i < U_WO; i += stride) {
        float4 a = ((const float4*)Wo)[2 * i];
        float4 b = ((const float4*)Wo)[2 * i + 1];
        f16x8 o;
        o[0] = (f16)a.x; o[1] = (f16)a.y; o[2] = (f16)a.z; o[3] = (f16)a.w;
        o[4] = (f16)b.x; o[5] = (f16)b.y; o[6] = (f16)b.z; o[7] = (f16)b.w;
        ((f16x8*)Wo16)[i] = o;
    }
}

// ---------------------------------------------------------------------------
// Gating MLP on precomputed pooled means. One block per span, 128 threads.
// ---------------------------------------------------------------------------
__global__ __launch_bounds__(128) void gate_mlp(
    const float* __restrict__ pooled,
    const float* __restrict__ gW1, const float* __restrict__ gb1,
    const float* __restrict__ gW2, const float* __restrict__ gb2,
    int* __restrict__ eidx, float* __restrict__ ewts,
    float* __restrict__ ent_partial) {
    int span = blockIdx.x;
    int tid = threadIdx.x;
    __shared__ float pl[C];
    __shared__ float h[GH];
    __shared__ float logits[E];

    for (int c = tid; c < C; c += 128) pl[c] = pooled[(size_t)span * C + c];
    __syncthreads();

    {
        float acc = gb1[tid];
        const float* wrow = gW1 + (size_t)tid * C;
        #pragma unroll 8
        for (int c = 0; c < C; ++c) acc += pl[c] * wrow[c];
        h[tid] = acc > 0.f ? acc : 0.f;
    }
    __syncthreads();

    if (tid < E) {
        float acc = gb2[tid];
        const float* wrow = gW2 + (size_t)tid * GH;
        #pragma unroll 8
        for (int j = 0; j < GH; ++j) acc += h[j] * wrow[j];
        logits[tid] = acc;
    }
    __syncthreads();

    if (tid == 0) {
        int i0 = 0; float v0 = logits[0];
        for (int e = 1; e < E; ++e) { if (logits[e] > v0) { v0 = logits[e]; i0 = e; } }
        int i1 = -1; float v1 = -3.0e38f;
        for (int e = 0; e < E; ++e) { if (e != i0 && logits[e] > v1) { v1 = logits[e]; i1 = e; } }
        float bq_ = expf(v1 - v0);
        float s = 1.f + bq_;
        float sm0 = 1.f / s;
        float sm1 = bq_ / s;
        eidx[span * 2 + 0] = i0;
        eidx[span * 2 + 1] = i1;
        ewts[span * 2 + 0] = sm0;
        ewts[span * 2 + 1] = sm1;
        float p0 = fmaxf(sm0, 1e-9f), p1 = fmaxf(sm1, 1e-9f);
        ent_partial[span] = sm0 * logf(p0) + sm1 * logf(p1);
    }
}

__global__ void entropy_kernel(const float* __restrict__ ent_partial, float* __restrict__ out_ent) {
    __shared__ float sh[256];
    int tid = threadIdx.x;
    sh[tid] = ent_partial[tid];
    __syncthreads();
    for (int s = 128; s > 0; s >>= 1) {
        if (tid < s) sh[tid] += sh[tid + s];
        __syncthreads();
    }
    if (tid == 0) *out_ent = -sh[0] * (1.0f / (float)BN);
}

// ---------------------------------------------------------------------------
// QKV v11: streaming (no LDS, no barriers) + EXPLICIT register double-buffer
// of the B (weight) fragments. Chunks processed in pairs with named buffers
// (static indexing): issue loads for chunk k+1, compute chunk k, alternate.
// In-flight loads get >= 1 chunk of compute x 3 interleaved waves (~430 cy)
// of latency cover. A fragments inline (all 4 waves read identical A units
// -> L1/L2 hits). grid (span=256, otile=3, proj=3), 256 threads = 4 waves,
// wave = 64 rows x 64 cols, cb = otile*4 + wv.
// For proj==V the output is written TRANSPOSED: vt[span][col][t].
// ---------------------------------------------------------------------------
__global__ __launch_bounds__(256, 3) void qkv_mfma(
    const f16* __restrict__ xh,
    const f16* __restrict__ Wq16, const float* __restrict__ bq,
    const f16* __restrict__ Wk16, const float* __restrict__ bk,
    const f16* __restrict__ Wv16, const float* __restrict__ bv,
    const int* __restrict__ eidx, const float* __restrict__ ewts,
    f16* __restrict__ q16, f16* __restrict__ k16, f16* __restrict__ vt)
{
    int span  = blockIdx.x;
    int otile = blockIdx.y;
    int proj  = blockIdx.z;

    const f16* W; const float* bias; f16* out;
    if (proj == 0)      { W = Wq16; bias = bq; out = q16; }
    else if (proj == 1) { W = Wk16; bias = bk; out = k16; }
    else                { W = Wv16; bias = bv; out = vt; }

    int e0 = eidx[span * 2 + 0], e1 = eidx[span * 2 + 1];
    float w0 = ewts[span * 2 + 0], w1 = ewts[span * 2 + 1];
    f16 w0h = (f16)w0, w1h = (f16)w1;

    int tid = threadIdx.x;
    int lane = tid & 63, wv = tid >> 6;
    int lr = lane & 15, lg = lane >> 4;
    int cb = otile * 4 + wv;              // 64-col block this wave owns

    const f16x8* xu  = (const f16x8*)xh + (size_t)span * 6144 + lane;
    const f16x8* wu0 = (const f16x8*)W + ((size_t)e0 * 12 + cb) * 6144 + lane;
    const f16x8* wu1 = (const f16x8*)W + ((size_t)e1 * 12 + cb) * 6144 + lane;

    f32x4 acc[4][4] = {};

    f16x8 b0A[4], b1A[4], b0B[4], b1B[4];
    // prologue: chunk 0 B fragments
    #pragma unroll
    for (int n = 0; n < 4; ++n) { b0A[n] = wu0[n * 64]; b1A[n] = wu1[n * 64]; }

    for (int kt2 = 0; kt2 < 12; ++kt2) {
        int ktA = kt2 * 2, ktB = ktA + 1;

        // issue chunk ktB's B loads (in flight during ktA compute)
        #pragma unroll
        for (int n = 0; n < 4; ++n) {
            b0B[n] = wu0[(ktB * 4 + n) * 64];
            b1B[n] = wu1[(ktB * 4 + n) * 64];
        }

        // compute chunk ktA from bufA
        {
            f16x8 af[4];
            #pragma unroll
            for (int m = 0; m < 4; ++m) af[m] = xu[(ktA * 4 + m) * 64];
            __builtin_amdgcn_s_setprio(1);
            #pragma unroll
            for (int n = 0; n < 4; ++n) {
                f16x8 bf = b0A[n] * w0h + b1A[n] * w1h;
                #pragma unroll
                for (int m = 0; m < 4; ++m)
                    acc[m][n] = __builtin_amdgcn_mfma_f32_16x16x32_f16(af[m], bf, acc[m][n], 0, 0, 0);
            }
            __builtin_amdgcn_s_setprio(0);
        }

        // issue chunk ktA+2's B loads (in flight during ktB compute)
        if (kt2 < 11) {
            #pragma unroll
            for (int n = 0; n < 4; ++n) {
                b0A[n] = wu0[((ktA + 2) * 4 + n) * 64];
                b1A[n] = wu1[((ktA + 2) * 4 + n) * 64];
            }
        }

        // compute chunk ktB from bufB
        {
            f16x8 af[4];
            #pragma unroll
            for (int m = 0; m < 4; ++m) af[m] = xu[(ktB * 4 + m) * 64];
            __builtin_amdgcn_s_setprio(1);
            #pragma unroll
            for (int n = 0; n < 4; ++n) {
                f16x8 bf = b0B[n] * w0h + b1B[n] * w1h;
                #pragma unroll
                for (int m = 0; m < 4; ++m)
                    acc[m][n] = __builtin_amdgcn_mfma_f32_16x16x32_f16(af[m], bf, acc[m][n], 0, 0, 0);
            }
            __builtin_amdgcn_s_setprio(0);
        }
    }

    if (proj == 2) {
        // transposed store: vt[span][col][t], t packed 4-at-a-time
        f16* vtb = out + (size_t)span * C * 64;
        #pragma unroll
        for (int n = 0; n < 4; ++n) {
            int col = cb * 64 + n * 16 + lr;
            float be = w0 * bias[(size_t)e0 * C + col] + w1 * bias[(size_t)e1 * C + col];
            #pragma unroll
            for (int m = 0; m < 4; ++m) {
                f16x4 pk;
                #pragma unroll
                for (int r = 0; r < 4; ++r) pk[r] = (f16)(acc[m][n][r] + be);
                *(f16x4*)&vtb[(size_t)col * 64 + m * 16 + lg * 4] = pk;
            }
        }
    } else {
        f16* outb = out + (size_t)span * 64 * C;
        #pragma unroll
        for (int n = 0; n < 4; ++n) {
            int col = cb * 64 + n * 16 + lr;
            float be = w0 * bias[(size_t)e0 * C + col] + w1 * bias[(size_t)e1 * C + col];
            #pragma unroll
            for (int m = 0; m < 4; ++m) {
                #pragma unroll
                for (int r = 0; r < 4; ++r) {
                    int row = m * 16 + lg * 4 + r;
                    outb[(size_t)row * C + col] = (f16)(acc[m][n][r] + be);
                }
            }
        }
    }
}

// ---------------------------------------------------------------------------
// MFMA attention. grid (NH, BN), 256 threads = 4 waves; wave mt owns q-rows
// [mt*16, mt*16+16). K and V^T staged in LDS (stride 72 halves = 144 B).
// All barriers lgkm-only (they order only LDS data).
// ---------------------------------------------------------------------------
__global__ __launch_bounds__(256) void attn_mfma(
    const f16* __restrict__ q16, const f16* __restrict__ k16,
    const f16* __restrict__ vt, f16* __restrict__ a16)
{
    int h = blockIdx.x, span = blockIdx.y;
    __shared__ __align__(16) f16 Klds[64 * 72];
    __shared__ __align__(16) f16 Vlds[64 * 72];
    __shared__ __align__(16) f16 Plds[64 * 72];

    int tid = threadIdx.x;
    int lane = tid & 63, mt = tid >> 6;
    int lr = lane & 15, lg = lane >> 4;

    const f16x8* ku = (const f16x8*)k16;
    const f16x8* vu = (const f16x8*)vt;
    #pragma unroll
    for (int i = 0; i < 2; ++i) {
        int id = tid + i * 256;
        int r = id >> 3, u = id & 7;
        *(f16x8*)&Klds[r * 72 + u * 8] = ku[(size_t)span * 6144 + (size_t)r * 96 + h * 8 + u];
        *(f16x8*)&Vlds[r * 72 + u * 8] = vu[(size_t)span * 6144 + (size_t)(h * 64 + r) * 8 + u];
    }
    // q loads issue here; consumed after the barrier (latency overlapped)
    const f16x8* qu = (const f16x8*)q16;
    f16x8 qa[2];
    #pragma unroll
    for (int kk = 0; kk < 2; ++kk)
        qa[kk] = qu[(size_t)span * 6144 + (size_t)(mt * 16 + lr) * 96 + h * 8 + kk * 4 + lg];

    LGKM_BARRIER();

    f32x4 accs[4] = {};
    #pragma unroll
    for (int nt = 0; nt < 4; ++nt) {
        #pragma unroll
        for (int kk = 0; kk < 2; ++kk) {
            f16x8 kb = *(const f16x8*)&Klds[(nt * 16 + lr) * 72 + kk * 32 + lg * 8];
            accs[nt] = __builtin_amdgcn_mfma_f32_16x16x32_f16(qa[kk], kb, accs[nt], 0, 0, 0);
        }
    }

    #pragma unroll
    for (int nt = 0; nt < 4; ++nt) accs[nt] *= 0.125f;
    f32x4 m4;
    #pragma unroll
    for (int r = 0; r < 4; ++r)
        m4[r] = fmaxf(fmaxf(accs[0][r], accs[1][r]), fmaxf(accs[2][r], accs[3][r]));
    #pragma unroll
    for (int st = 1; st < 16; st <<= 1) {
        #pragma unroll
        for (int r = 0; r < 4; ++r) m4[r] = fmaxf(m4[r], __shfl_xor(m4[r], st));
    }
    f32x4 ps[4];
    f32x4 sum4 = {0.f, 0.f, 0.f, 0.f};
    #pragma unroll
    for (int nt = 0; nt < 4; ++nt)
        #pragma unroll
        for (int r = 0; r < 4; ++r) {
            ps[nt][r] = __expf(accs[nt][r] - m4[r]);
            sum4[r] += ps[nt][r];
        }
    #pragma unroll
    for (int st = 1; st < 16; st <<= 1) {
        #pragma unroll
        for (int r = 0; r < 4; ++r) sum4[r] += __shfl_xor(sum4[r], st);
    }
    f32x4 inv4;
    #pragma unroll
    for (int r = 0; r < 4; ++r) inv4[r] = 1.0f / sum4[r];

    #pragma unroll
    for (int nt = 0; nt < 4; ++nt)
        #pragma unroll
        for (int r = 0; r < 4; ++r)
            Plds[(mt * 16 + lg * 4 + r) * 72 + nt * 16 + lr] = (f16)ps[nt][r];

    LGKM_BARRIER();

    f16x8 pa[2];
    #pragma unroll
    for (int kkt = 0; kkt < 2; ++kkt)
        pa[kkt] = *(const f16x8*)&Plds[(mt * 16 + lr) * 72 + kkt * 32 + lg * 8];
    f32x4 acco[4] = {};
    #pragma unroll
    for (int nt = 0; nt < 4; ++nt) {
        #pragma unroll
        for (int kkt = 0; kkt < 2; ++kkt) {
            f16x8 vb = *(const f16x8*)&Vlds[(nt * 16 + lr) * 72 + kkt * 32 + lg * 8];
            acco[nt] = __builtin_amdgcn_mfma_f32_16x16x32_f16(pa[kkt], vb, acco[nt], 0, 0, 0);
        }
    }

    #pragma unroll
    for (int nt = 0; nt < 4; ++nt)
        #pragma unroll
        for (int r = 0; r < 4; ++r)
            Klds[(mt * 16 + lg * 4 + r) * 72 + nt * 16 + lr] = (f16)(acco[nt][r] * inv4[r]);

    LGKM_BARRIER();

    int row = mt * 16 + (lane >> 2);
    int u2 = (lane & 3) * 2;
    f16x8 o0 = *(const f16x8*)&Klds[row * 72 + u2 * 8];
    f16x8 o1 = *(const f16x8*)&Klds[row * 72 + u2 * 8 + 8];
    f16x8* au = (f16x8*)a16;
    au[(size_t)span * 6144 + (size_t)row * 96 + h * 8 + u2]     = o0;
    au[(size_t)span * 6144 + (size_t)row * 96 + h * 8 + u2 + 1] = o1;
}

// ---------------------------------------------------------------------------
// Output projection via f16 MFMA. grid (rt=128, otile=3), 512 threads (8 waves).
// Register prefetch in flight across lgkm-only barriers.
// ---------------------------------------------------------------------------
__global__ __launch_bounds__(512) void outproj_mfma(
    const f16* __restrict__ ah, const f16* __restrict__ Wo16,
    const float* __restrict__ bo, float* __restrict__ Y)
{
    int rt = blockIdx.x;
    int otile = blockIdx.y;

    __shared__ f16x8 as_u[128 * 8];   // 16 KB
    __shared__ f16x8 ws_u[256 * 8];   // 32 KB

    const f16x8* au  = (const f16x8*)(ah + (size_t)rt * 128 * C);
    const f16x8* Wou = (const f16x8*)(Wo16 + (size_t)otile * 256 * C);

    int tid = threadIdx.x;
    int lane = tid & 63, wv = tid >> 6;
    int lr = lane & 15, lg = lane >> 4;
    int wm = (wv >> 2) * 64;
    int wn = (wv & 3) * 64;

    f32x4 acc[4][4] = {};

    f16x8 ar_[2], wr_[4];
    // prologue: prefetch chunk 0
    #pragma unroll
    for (int i = 0; i < 2; ++i) {
        int id = tid + i * 512;
        ar_[i] = au[(size_t)(id >> 3) * 96 + (id & 7)];
    }
    #pragma unroll
    for (int i = 0; i < 4; ++i) {
        int id = tid + i * 512;
        wr_[i] = Wou[(size_t)(id >> 3) * 96 + (id & 7)];
    }

    for (int kc8 = 0; kc8 < 96; kc8 += 8) {
        // stage current regs -> LDS (swizzled)
        #pragma unroll
        for (int i = 0; i < 2; ++i) {
            int id = tid + i * 512;
            int r = id >> 3, u = id & 7;
            as_u[r * 8 + (u ^ (r & 7))] = ar_[i];
        }
        #pragma unroll
        for (int i = 0; i < 4; ++i) {
            int id = tid + i * 512;
            int r = id >> 3, u = id & 7;
            ws_u[r * 8 + (u ^ (r & 7))] = wr_[i];
        }

        // prefetch next chunk; stays in flight across both barriers
        if (kc8 < 88) {
            int kn = kc8 + 8;
            #pragma unroll
            for (int i = 0; i < 2; ++i) {
                int id = tid + i * 512;
                ar_[i] = au[(size_t)(id >> 3) * 96 + kn + (id & 7)];
            }
            #pragma unroll
            for (int i = 0; i < 4; ++i) {
                int id = tid + i * 512;
                wr_[i] = Wou[(size_t)(id >> 3) * 96 + kn + (id & 7)];
            }
        }

        LGKM_BARRIER();

        #pragma unroll
        for (int kk = 0; kk < 2; ++kk) {
            int ub = kk * 4 + lg;
            f16x8 afrag[4], bfrag[4];
            #pragma unroll
            for (int m = 0; m < 4; ++m) {
                int r = wm + m * 16 + lr;
                afrag[m] = as_u[r * 8 + (ub ^ (r & 7))];
            }
            #pragma unroll
            for (int n = 0; n < 4; ++n) {
                int r = wn + n * 16 + lr;
                bfrag[n] = ws_u[r * 8 + (ub ^ (r & 7))];
            }
            #pragma unroll
            for (int m = 0; m < 4; ++m)
                #pragma unroll
                for (int n = 0; n < 4; ++n)
                    acc[m][n] = __builtin_amdgcn_mfma_f32_16x16x32_f16(afrag[m], bfrag[n], acc[m][n], 0, 0, 0);
        }

        LGKM_BARRIER();
    }

    #pragma unroll
    for (int n = 0; n < 4; ++n) {
        int col = otile * 256 + wn + n * 16 + lr;
        float be = bo[col];
        #pragma unroll
        for (int m = 0; m < 4; ++m) {
            #pragma unroll
            for (int r = 0; r < 4; ++r) {
                int row = rt * 128 + wm + m * 16 + lg * 4 + r;
                Y[(size_t)row * C + col] = acc[m][n][r] + be;
            }
        }
    }
}

// ---------------------------------------------------------------------------
extern "C" void kernel_launch(void* const* d_in, const int* in_sizes, int n_in,
                              void* d_out, int out_size, void* d_ws, size_t ws_size,
                              hipStream_t stream) {
    const float* x   = (const float*)d_in[0];
    const float* Wq  = (const float*)d_in[1];
    const float* bq  = (const float*)d_in[2];
    const float* Wk  = (const float*)d_in[3];
    const float* bk  = (const float*)d_in[4];
    const float* Wv  = (const float*)d_in[5];
    const float* bv  = (const float*)d_in[6];
    const float* gW1 = (const float*)d_in[7];
    const float* gb1 = (const float*)d_in[8];
    const float* gW2 = (const float*)d_in[9];
    const float* gb2 = (const float*)d_in[10];
    const float* Wo  = (const float*)d_in[11];
    const float* bo  = (const float*)d_in[12];

    float* out = (float*)d_out;

    char* ws = (char*)d_ws;
    const size_t h_btc = (size_t)BTC * sizeof(f16);            // 25,165,824
    f16* x16  = (f16*)(ws);
    f16* q16  = (f16*)(ws + 1 * h_btc);
    f16* k16  = (f16*)(ws + 2 * h_btc);
    f16* vt16 = (f16*)(ws + 3 * h_btc);   // transposed V: [span][col][t]
    f16* a16  = (f16*)(ws + 4 * h_btc);
    size_t off = 5 * h_btc;
    const size_t wsz = (size_t)E * C * C * sizeof(f16);        // 4,718,592
    f16* Wq16 = (f16*)(ws + off); off += wsz;
    f16* Wk16 = (f16*)(ws + off); off += wsz;
    f16* Wv16 = (f16*)(ws + off); off += wsz;
    f16* Wo16 = (f16*)(ws + off); off += (size_t)C * C * sizeof(f16);
    int*   eidx = (int*)(ws + off); off += 2048;
    float* ewts = (float*)(ws + off); off += 2048;
    float* entp = (float*)(ws + off); off += 1024;
    float* pooled = (float*)(ws + off); off += (size_t)BN * C * sizeof(float);

    cvt_x_pool<<<dim3(BN), dim3(768), 0, stream>>>(x, x16, pooled);
    cvt_w_frag<<<dim3(48, 3), dim3(768), 0, stream>>>(Wq, Wk, Wv,
                                                      Wq16, Wk16, Wv16);
    cvt_wo<<<dim3(288), dim3(256), 0, stream>>>(Wo, Wo16);
    gate_mlp<<<dim3(BN), dim3(128), 0, stream>>>(pooled, gW1, gb1, gW2, gb2,
                                                 eidx, ewts, entp);
    entropy_kernel<<<dim3(1), dim3(256), 0, stream>>>(entp, out + BTC);

    qkv_mfma<<<dim3(BN, 3, 3), dim3(256), 0, stream>>>(x16, Wq16, bq, Wk16, bk, Wv16, bv,
                                                       eidx, ewts, q16, k16, vt16);
    attn_mfma<<<dim3(NH, BN), dim3(256), 0, stream>>>(q16, k16, vt16, a16);
    outproj_mfma<<<dim3(128, 3), dim3(512), 0, stream>>>(a16, Wo16, bo, out);
}

// Round 11
// 209.244 us; speedup vs baseline: 1.1442x; 1.0027x over previous
//
#include <hip/hip_runtime.h>
#include <hip/hip_bf16.h>
#include <hip/hip_fp16.h>

typedef _Float16 f16;
typedef _Float16 f16x8 __attribute__((ext_vector_type(8)));
typedef _Float16 f16x4 __attribute__((ext_vector_type(4)));
typedef float f32x4 __attribute__((ext_vector_type(4)));

// Problem constants
constexpr int B = 4;
constexpr int T = 4096;
constexpr int C = 768;
constexpr int NH = 12;
constexpr int DH = 64;
constexpr int E = 4;
constexpr int SPAN = 64;
constexpr int N = T / SPAN;
constexpr int BN = B * N;       // 256 spans
constexpr int GH = 128;
constexpr int BTC = B * T * C;  // 12,582,912

constexpr int U_WO = C * C / 8;            //    73,728

// lgkm-only barrier: no vmcnt drain (in-flight global loads stay in flight)
#define LGKM_BARRIER()                                      \
    do {                                                    \
        asm volatile("s_waitcnt lgkmcnt(0)" ::: "memory");  \
        __builtin_amdgcn_s_barrier();                       \
        __builtin_amdgcn_sched_barrier(0);                  \
    } while (0)

// ---------------------------------------------------------------------------
// x f32->f16 conversion fused with per-span mean pooling.
// Coalesced f32 read -> convert (+pool) -> LDS (XOR-swizzled) -> COALESCED
// fragment-order global write: unit = span*6144 + (kt*4 + m)*64 + lg*16 + lr
// ---------------------------------------------------------------------------
__global__ __launch_bounds__(768) void cvt_x_pool(
    const float* __restrict__ x, f16* __restrict__ x16,
    float* __restrict__ pooled) {
    int span = blockIdx.x;
    int tid = threadIdx.x;
    int u = tid % 96, rg = tid / 96;     // rg 0..7
    __shared__ f16x8 xlds[6144];         // 96 KB
    __shared__ float part[8][C];         // 24 KB

    const float* xb = x + (size_t)span * SPAN * C;
    float a8[8] = {};
    #pragma unroll
    for (int j = 0; j < 8; ++j) {
        int r = rg * 8 + j;
        const float4* s = (const float4*)(xb + (size_t)r * C + u * 8);
        float4 A = s[0], Bv = s[1];
        f16x8 o;
        o[0] = (f16)A.x;  o[1] = (f16)A.y;  o[2] = (f16)A.z;  o[3] = (f16)A.w;
        o[4] = (f16)Bv.x; o[5] = (f16)Bv.y; o[6] = (f16)Bv.z; o[7] = (f16)Bv.w;
        xlds[r * 96 + (u & ~7) + ((u & 7) ^ (r & 7))] = o;
        a8[0] += A.x;  a8[1] += A.y;  a8[2] += A.z;  a8[3] += A.w;
        a8[4] += Bv.x; a8[5] += Bv.y; a8[6] += Bv.z; a8[7] += Bv.w;
    }
    #pragma unroll
    for (int j = 0; j < 8; ++j) part[rg][u * 8 + j] = a8[j];
    __syncthreads();
    float s = 0.f;
    #pragma unroll
    for (int g = 0; g < 8; ++g) s += part[g][tid];
    pooled[(size_t)span * C + tid] = s * (1.f / 64.f);

    // coalesced fragment-order write: unit = (kt*4+m)*64 + lg*16 + lr
    f16x8* xo = (f16x8*)x16 + (size_t)span * 6144;
    #pragma unroll
    for (int j = 0; j < 8; ++j) {
        int un = tid + j * 768;
        int lr = un & 15, lg = (un >> 4) & 3, m = (un >> 6) & 3, kt = un >> 8;
        int row = m * 16 + lr, ku = kt * 4 + lg;
        xo[un] = xlds[row * 96 + (ku & ~7) + ((ku & 7) ^ (row & 7))];
    }
}

// ---------------------------------------------------------------------------
// Wq/Wk/Wv f32 -> f16 in MFMA B-FRAGMENT layout, coalesced both sides via
// LDS transpose. One block per (tensor, e, cb): 64 output rows x 768 K.
//   dst unit index = (e*12 + cb)*6144 + (kt*4 + n)*64 + lg*16 + lr
// ---------------------------------------------------------------------------
__global__ __launch_bounds__(768) void cvt_w_frag(
    const float* __restrict__ Wq, const float* __restrict__ Wk,
    const float* __restrict__ Wv,
    f16* __restrict__ Wq16, f16* __restrict__ Wk16, f16* __restrict__ Wv16) {
    int slice = blockIdx.x;          // 0..47 = e*12 + cb
    int tsel  = blockIdx.y;          // 0..2
    const float* src; f16* dst;
    if (tsel == 0)      { src = Wq; dst = Wq16; }
    else if (tsel == 1) { src = Wk; dst = Wk16; }
    else                { src = Wv; dst = Wv16; }
    int e = slice / 12, cb = slice % 12;

    __shared__ f16x8 wlds[6144];     // 96 KB
    int tid = threadIdx.x;

    // read: 64 rows x 96 units, coalesced
    const float* wb = src + ((size_t)e * C + cb * 64) * C;
    #pragma unroll
    for (int j = 0; j < 8; ++j) {
        int g = tid + j * 768;
        int row = g / 96, ku = g % 96;
        const float4* sp = (const float4*)(wb + (size_t)row * C + ku * 8);
        float4 A = sp[0], Bv = sp[1];
        f16x8 o;
        o[0] = (f16)A.x;  o[1] = (f16)A.y;  o[2] = (f16)A.z;  o[3] = (f16)A.w;
        o[4] = (f16)Bv.x; o[5] = (f16)Bv.y; o[6] = (f16)Bv.z; o[7] = (f16)Bv.w;
        wlds[row * 96 + (ku & ~7) + ((ku & 7) ^ (row & 7))] = o;
    }
    __syncthreads();

    // write: fragment order, coalesced
    f16x8* wo = (f16x8*)dst + (size_t)slice * 6144;
    #pragma unroll
    for (int j = 0; j < 8; ++j) {
        int un = tid + j * 768;
        int lr = un & 15, lg = (un >> 4) & 3, nn = (un >> 6) & 3, kt = un >> 8;
        int row = nn * 16 + lr, ku = kt * 4 + lg;
        wo[un] = wlds[row * 96 + (ku & ~7) + ((ku & 7) ^ (row & 7))];
    }
}

// ---------------------------------------------------------------------------
// Wo f32 -> f16, row-major (outproj stages via LDS as before).
// ---------------------------------------------------------------------------
__global__ void cvt_wo(const float* __restrict__ Wo, f16* __restrict__ Wo16) {
    int i = blockIdx.x * blockDim.x + threadIdx.x;
    int stride = gridDim.x * blockDim.x;
    for (; i < U_WO; i += stride) {
        float4 a = ((const float4*)Wo)[2 * i];
        float4 b = ((const float4*)Wo)[2 * i + 1];
        f16x8 o;
        o[0] = (f16)a.x; o[1] = (f16)a.y; o[2] = (f16)a.z; o[3] = (f16)a.w;
        o[4] = (f16)b.x; o[5] = (f16)b.y; o[6] = (f16)b.z; o[7] = (f16)b.w;
        ((f16x8*)Wo16)[i] = o;
    }
}

// ---------------------------------------------------------------------------
// Gating MLP on precomputed pooled means. One block per span, 128 threads.
// ---------------------------------------------------------------------------
__global__ __launch_bounds__(128) void gate_mlp(
    const float* __restrict__ pooled,
    const float* __restrict__ gW1, const float* __restrict__ gb1,
    const float* __restrict__ gW2, const float* __restrict__ gb2,
    int* __restrict__ eidx, float* __restrict__ ewts,
    float* __restrict__ ent_partial) {
    int span = blockIdx.x;
    int tid = threadIdx.x;
    __shared__ float pl[C];
    __shared__ float h[GH];
    __shared__ float logits[E];

    for (int c = tid; c < C; c += 128) pl[c] = pooled[(size_t)span * C + c];
    __syncthreads();

    {
        float acc = gb1[tid];
        const float* wrow = gW1 + (size_t)tid * C;
        #pragma unroll 8
        for (int c = 0; c < C; ++c) acc += pl[c] * wrow[c];
        h[tid] = acc > 0.f ? acc : 0.f;
    }
    __syncthreads();

    if (tid < E) {
        float acc = gb2[tid];
        const float* wrow = gW2 + (size_t)tid * GH;
        #pragma unroll 8
        for (int j = 0; j < GH; ++j) acc += h[j] * wrow[j];
        logits[tid] = acc;
    }
    __syncthreads();

    if (tid == 0) {
        int i0 = 0; float v0 = logits[0];
        for (int e = 1; e < E; ++e) { if (logits[e] > v0) { v0 = logits[e]; i0 = e; } }
        int i1 = -1; float v1 = -3.0e38f;
        for (int e = 0; e < E; ++e) { if (e != i0 && logits[e] > v1) { v1 = logits[e]; i1 = e; } }
        float bq_ = expf(v1 - v0);
        float s = 1.f + bq_;
        float sm0 = 1.f / s;
        float sm1 = bq_ / s;
        eidx[span * 2 + 0] = i0;
        eidx[span * 2 + 1] = i1;
        ewts[span * 2 + 0] = sm0;
        ewts[span * 2 + 1] = sm1;
        float p0 = fmaxf(sm0, 1e-9f), p1 = fmaxf(sm1, 1e-9f);
        ent_partial[span] = sm0 * logf(p0) + sm1 * logf(p1);
    }
}

__global__ void entropy_kernel(const float* __restrict__ ent_partial, float* __restrict__ out_ent) {
    __shared__ float sh[256];
    int tid = threadIdx.x;
    sh[tid] = ent_partial[tid];
    __syncthreads();
    for (int s = 128; s > 0; s >>= 1) {
        if (tid < s) sh[tid] += sh[tid + s];
        __syncthreads();
    }
    if (tid == 0) *out_ent = -sh[0] * (1.0f / (float)BN);
}

// ---------------------------------------------------------------------------
// QKV v12: streaming + DEEP register pipeline.
//   - B fragments: 3-slot rotation, prefetch distance 2 (issue chunk k+2's
//     8 loads while computing chunk k) -> ~2 chunks of latency cover.
//   - A fragments: 2-slot rotation, prefetch distance 1 (kills the
//     load-then-immediately-MFMA stall v11 had on the A side).
//   - fully unrolled 24-chunk loop: all buffer indices compile-time (no
//     scratch); __launch_bounds__(256,2) so ~204 combined regs don't spill.
// grid (span=256, otile=3, proj=3), 256 threads = 4 waves, wave = 64x64,
// cb = otile*4 + wv. For proj==V output written TRANSPOSED vt[span][col][t].
// ---------------------------------------------------------------------------
__global__ __launch_bounds__(256, 2) void qkv_mfma(
    const f16* __restrict__ xh,
    const f16* __restrict__ Wq16, const float* __restrict__ bq,
    const f16* __restrict__ Wk16, const float* __restrict__ bk,
    const f16* __restrict__ Wv16, const float* __restrict__ bv,
    const int* __restrict__ eidx, const float* __restrict__ ewts,
    f16* __restrict__ q16, f16* __restrict__ k16, f16* __restrict__ vt)
{
    int span  = blockIdx.x;
    int otile = blockIdx.y;
    int proj  = blockIdx.z;

    const f16* W; const float* bias; f16* out;
    if (proj == 0)      { W = Wq16; bias = bq; out = q16; }
    else if (proj == 1) { W = Wk16; bias = bk; out = k16; }
    else                { W = Wv16; bias = bv; out = vt; }

    int e0 = eidx[span * 2 + 0], e1 = eidx[span * 2 + 1];
    float w0 = ewts[span * 2 + 0], w1 = ewts[span * 2 + 1];
    f16 w0h = (f16)w0, w1h = (f16)w1;

    int tid = threadIdx.x;
    int lane = tid & 63, wv = tid >> 6;
    int lr = lane & 15, lg = lane >> 4;
    int cb = otile * 4 + wv;              // 64-col block this wave owns

    const f16x8* xu  = (const f16x8*)xh + (size_t)span * 6144 + lane;
    const f16x8* wu0 = (const f16x8*)W + ((size_t)e0 * 12 + cb) * 6144 + lane;
    const f16x8* wu1 = (const f16x8*)W + ((size_t)e1 * 12 + cb) * 6144 + lane;

    f32x4 acc[4][4] = {};

    f16x8 bb0[3][4], bb1[3][4];   // B rotation, 3 slots
    f16x8 aa[2][4];               // A rotation, 2 slots

    // prologue: B chunks 0,1; A chunk 0
    #pragma unroll
    for (int n = 0; n < 4; ++n) { bb0[0][n] = wu0[n * 64];        bb1[0][n] = wu1[n * 64]; }
    #pragma unroll
    for (int n = 0; n < 4; ++n) { bb0[1][n] = wu0[(4 + n) * 64];  bb1[1][n] = wu1[(4 + n) * 64]; }
    #pragma unroll
    for (int m = 0; m < 4; ++m) aa[0][m] = xu[m * 64];

    #pragma unroll
    for (int kt = 0; kt < 24; ++kt) {
        // issue B loads for chunk kt+2 into slot (kt+2)%3 (free: last read at kt-1)
        if (kt < 22) {
            int kn = kt + 2, s = (kt + 2) % 3;
            #pragma unroll
            for (int n = 0; n < 4; ++n) {
                bb0[s][n] = wu0[(kn * 4 + n) * 64];
                bb1[s][n] = wu1[(kn * 4 + n) * 64];
            }
        }
        // issue A loads for chunk kt+1 into slot (kt+1)&1
        if (kt < 23) {
            int kn = kt + 1, s = (kt + 1) & 1;
            #pragma unroll
            for (int m = 0; m < 4; ++m) aa[s][m] = xu[(kn * 4 + m) * 64];
        }

        // compute chunk kt
        {
            int s3 = kt % 3, s2 = kt & 1;
            __builtin_amdgcn_s_setprio(1);
            #pragma unroll
            for (int n = 0; n < 4; ++n) {
                f16x8 bf = bb0[s3][n] * w0h + bb1[s3][n] * w1h;
                #pragma unroll
                for (int m = 0; m < 4; ++m)
                    acc[m][n] = __builtin_amdgcn_mfma_f32_16x16x32_f16(aa[s2][m], bf, acc[m][n], 0, 0, 0);
            }
            __builtin_amdgcn_s_setprio(0);
        }
    }

    if (proj == 2) {
        // transposed store: vt[span][col][t], t packed 4-at-a-time
        f16* vtb = out + (size_t)span * C * 64;
        #pragma unroll
        for (int n = 0; n < 4; ++n) {
            int col = cb * 64 + n * 16 + lr;
            float be = w0 * bias[(size_t)e0 * C + col] + w1 * bias[(size_t)e1 * C + col];
            #pragma unroll
            for (int m = 0; m < 4; ++m) {
                f16x4 pk;
                #pragma unroll
                for (int r = 0; r < 4; ++r) pk[r] = (f16)(acc[m][n][r] + be);
                *(f16x4*)&vtb[(size_t)col * 64 + m * 16 + lg * 4] = pk;
            }
        }
    } else {
        f16* outb = out + (size_t)span * 64 * C;
        #pragma unroll
        for (int n = 0; n < 4; ++n) {
            int col = cb * 64 + n * 16 + lr;
            float be = w0 * bias[(size_t)e0 * C + col] + w1 * bias[(size_t)e1 * C + col];
            #pragma unroll
            for (int m = 0; m < 4; ++m) {
                #pragma unroll
                for (int r = 0; r < 4; ++r) {
                    int row = m * 16 + lg * 4 + r;
                    outb[(size_t)row * C + col] = (f16)(acc[m][n][r] + be);
                }
            }
        }
    }
}

// ---------------------------------------------------------------------------
// MFMA attention. grid (NH, BN), 256 threads = 4 waves; wave mt owns q-rows
// [mt*16, mt*16+16). K and V^T staged in LDS (stride 72 halves = 144 B).
// All barriers lgkm-only (they order only LDS data).
// ---------------------------------------------------------------------------
__global__ __launch_bounds__(256) void attn_mfma(
    const f16* __restrict__ q16, const f16* __restrict__ k16,
    const f16* __restrict__ vt, f16* __restrict__ a16)
{
    int h = blockIdx.x, span = blockIdx.y;
    __shared__ __align__(16) f16 Klds[64 * 72];
    __shared__ __align__(16) f16 Vlds[64 * 72];
    __shared__ __align__(16) f16 Plds[64 * 72];

    int tid = threadIdx.x;
    int lane = tid & 63, mt = tid >> 6;
    int lr = lane & 15, lg = lane >> 4;

    const f16x8* ku = (const f16x8*)k16;
    const f16x8* vu = (const f16x8*)vt;
    #pragma unroll
    for (int i = 0; i < 2; ++i) {
        int id = tid + i * 256;
        int r = id >> 3, u = id & 7;
        *(f16x8*)&Klds[r * 72 + u * 8] = ku[(size_t)span * 6144 + (size_t)r * 96 + h * 8 + u];
        *(f16x8*)&Vlds[r * 72 + u * 8] = vu[(size_t)span * 6144 + (size_t)(h * 64 + r) * 8 + u];
    }
    // q loads issue here; consumed after the barrier (latency overlapped)
    const f16x8* qu = (const f16x8*)q16;
    f16x8 qa[2];
    #pragma unroll
    for (int kk = 0; kk < 2; ++kk)
        qa[kk] = qu[(size_t)span * 6144 + (size_t)(mt * 16 + lr) * 96 + h * 8 + kk * 4 + lg];

    LGKM_BARRIER();

    f32x4 accs[4] = {};
    #pragma unroll
    for (int nt = 0; nt < 4; ++nt) {
        #pragma unroll
        for (int kk = 0; kk < 2; ++kk) {
            f16x8 kb = *(const f16x8*)&Klds[(nt * 16 + lr) * 72 + kk * 32 + lg * 8];
            accs[nt] = __builtin_amdgcn_mfma_f32_16x16x32_f16(qa[kk], kb, accs[nt], 0, 0, 0);
        }
    }

    #pragma unroll
    for (int nt = 0; nt < 4; ++nt) accs[nt] *= 0.125f;
    f32x4 m4;
    #pragma unroll
    for (int r = 0; r < 4; ++r)
        m4[r] = fmaxf(fmaxf(accs[0][r], accs[1][r]), fmaxf(accs[2][r], accs[3][r]));
    #pragma unroll
    for (int st = 1; st < 16; st <<= 1) {
        #pragma unroll
        for (int r = 0; r < 4; ++r) m4[r] = fmaxf(m4[r], __shfl_xor(m4[r], st));
    }
    f32x4 ps[4];
    f32x4 sum4 = {0.f, 0.f, 0.f, 0.f};
    #pragma unroll
    for (int nt = 0; nt < 4; ++nt)
        #pragma unroll
        for (int r = 0; r < 4; ++r) {
            ps[nt][r] = __expf(accs[nt][r] - m4[r]);
            sum4[r] += ps[nt][r];
        }
    #pragma unroll
    for (int st = 1; st < 16; st <<= 1) {
        #pragma unroll
        for (int r = 0; r < 4; ++r) sum4[r] += __shfl_xor(sum4[r], st);
    }
    f32x4 inv4;
    #pragma unroll
    for (int r = 0; r < 4; ++r) inv4[r] = 1.0f / sum4[r];

    #pragma unroll
    for (int nt = 0; nt < 4; ++nt)
        #pragma unroll
        for (int r = 0; r < 4; ++r)
            Plds[(mt * 16 + lg * 4 + r) * 72 + nt * 16 + lr] = (f16)ps[nt][r];

    LGKM_BARRIER();

    f16x8 pa[2];
    #pragma unroll
    for (int kkt = 0; kkt < 2; ++kkt)
        pa[kkt] = *(const f16x8*)&Plds[(mt * 16 + lr) * 72 + kkt * 32 + lg * 8];
    f32x4 acco[4] = {};
    #pragma unroll
    for (int nt = 0; nt < 4; ++nt) {
        #pragma unroll
        for (int kkt = 0; kkt < 2; ++kkt) {
            f16x8 vb = *(const f16x8*)&Vlds[(nt * 16 + lr) * 72 + kkt * 32 + lg * 8];
            acco[nt] = __builtin_amdgcn_mfma_f32_16x16x32_f16(pa[kkt], vb, acco[nt], 0, 0, 0);
        }
    }

    #pragma unroll
    for (int nt = 0; nt < 4; ++nt)
        #pragma unroll
        for (int r = 0; r < 4; ++r)
            Klds[(mt * 16 + lg * 4 + r) * 72 + nt * 16 + lr] = (f16)(acco[nt][r] * inv4[r]);

    LGKM_BARRIER();

    int row = mt * 16 + (lane >> 2);
    int u2 = (lane & 3) * 2;
    f16x8 o0 = *(const f16x8*)&Klds[row * 72 + u2 * 8];
    f16x8 o1 = *(const f16x8*)&Klds[row * 72 + u2 * 8 + 8];
    f16x8* au = (f16x8*)a16;
    au[(size_t)span * 6144 + (size_t)row * 96 + h * 8 + u2]     = o0;
    au[(size_t)span * 6144 + (size_t)row * 96 + h * 8 + u2 + 1] = o1;
}

// ---------------------------------------------------------------------------
// Output projection via f16 MFMA. grid (rt=128, otile=3), 512 threads (8 waves).
// Register prefetch in flight across lgkm-only barriers.
// ---------------------------------------------------------------------------
__global__ __launch_bounds__(512) void outproj_mfma(
    const f16* __restrict__ ah, const f16* __restrict__ Wo16,
    const float* __restrict__ bo, float* __restrict__ Y)
{
    int rt = blockIdx.x;
    int otile = blockIdx.y;

    __shared__ f16x8 as_u[128 * 8];   // 16 KB
    __shared__ f16x8 ws_u[256 * 8];   // 32 KB

    const f16x8* au  = (const f16x8*)(ah + (size_t)rt * 128 * C);
    const f16x8* Wou = (const f16x8*)(Wo16 + (size_t)otile * 256 * C);

    int tid = threadIdx.x;
    int lane = tid & 63, wv = tid >> 6;
    int lr = lane & 15, lg = lane >> 4;
    int wm = (wv >> 2) * 64;
    int wn = (wv & 3) * 64;

    f32x4 acc[4][4] = {};

    f16x8 ar_[2], wr_[4];
    // prologue: prefetch chunk 0
    #pragma unroll
    for (int i = 0; i < 2; ++i) {
        int id = tid + i * 512;
        ar_[i] = au[(size_t)(id >> 3) * 96 + (id & 7)];
    }
    #pragma unroll
    for (int i = 0; i < 4; ++i) {
        int id = tid + i * 512;
        wr_[i] = Wou[(size_t)(id >> 3) * 96 + (id & 7)];
    }

    for (int kc8 = 0; kc8 < 96; kc8 += 8) {
        // stage current regs -> LDS (swizzled)
        #pragma unroll
        for (int i = 0; i < 2; ++i) {
            int id = tid + i * 512;
            int r = id >> 3, u = id & 7;
            as_u[r * 8 + (u ^ (r & 7))] = ar_[i];
        }
        #pragma unroll
        for (int i = 0; i < 4; ++i) {
            int id = tid + i * 512;
            int r = id >> 3, u = id & 7;
            ws_u[r * 8 + (u ^ (r & 7))] = wr_[i];
        }

        // prefetch next chunk; stays in flight across both barriers
        if (kc8 < 88) {
            int kn = kc8 + 8;
            #pragma unroll
            for (int i = 0; i < 2; ++i) {
                int id = tid + i * 512;
                ar_[i] = au[(size_t)(id >> 3) * 96 + kn + (id & 7)];
            }
            #pragma unroll
            for (int i = 0; i < 4; ++i) {
                int id = tid + i * 512;
                wr_[i] = Wou[(size_t)(id >> 3) * 96 + kn + (id & 7)];
            }
        }

        LGKM_BARRIER();

        #pragma unroll
        for (int kk = 0; kk < 2; ++kk) {
            int ub = kk * 4 + lg;
            f16x8 afrag[4], bfrag[4];
            #pragma unroll
            for (int m = 0; m < 4; ++m) {
                int r = wm + m * 16 + lr;
                afrag[m] = as_u[r * 8 + (ub ^ (r & 7))];
            }
            #pragma unroll
            for (int n = 0; n < 4; ++n) {
                int r = wn + n * 16 + lr;
                bfrag[n] = ws_u[r * 8 + (ub ^ (r & 7))];
            }
            #pragma unroll
            for (int m = 0; m < 4; ++m)
                #pragma unroll
                for (int n = 0; n < 4; ++n)
                    acc[m][n] = __builtin_amdgcn_mfma_f32_16x16x32_f16(afrag[m], bfrag[n], acc[m][n], 0, 0, 0);
        }

        LGKM_BARRIER();
    }

    #pragma unroll
    for (int n = 0; n < 4; ++n) {
        int col = otile * 256 + wn + n * 16 + lr;
        float be = bo[col];
        #pragma unroll
        for (int m = 0; m < 4; ++m) {
            #pragma unroll
            for (int r = 0; r < 4; ++r) {
                int row = rt * 128 + wm + m * 16 + lg * 4 + r;
                Y[(size_t)row * C + col] = acc[m][n][r] + be;
            }
        }
    }
}

// ---------------------------------------------------------------------------
extern "C" void kernel_launch(void* const* d_in, const int* in_sizes, int n_in,
                              void* d_out, int out_size, void* d_ws, size_t ws_size,
                              hipStream_t stream) {
    const float* x   = (const float*)d_in[0];
    const float* Wq  = (const float*)d_in[1];
    const float* bq  = (const float*)d_in[2];
    const float* Wk  = (const float*)d_in[3];
    const float* bk  = (const float*)d_in[4];
    const float* Wv  = (const float*)d_in[5];
    const float* bv  = (const float*)d_in[6];
    const float* gW1 = (const float*)d_in[7];
    const float* gb1 = (const float*)d_in[8];
    const float* gW2 = (const float*)d_in[9];
    const float* gb2 = (const float*)d_in[10];
    const float* Wo  = (const float*)d_in[11];
    const float* bo  = (const float*)d_in[12];

    float* out = (float*)d_out;

    char* ws = (char*)d_ws;
    const size_t h_btc = (size_t)BTC * sizeof(f16);            // 25,165,824
    f16* x16  = (f16*)(ws);
    f16* q16  = (f16*)(ws + 1 * h_btc);
    f16* k16  = (f16*)(ws + 2 * h_btc);
    f16* vt16 = (f16*)(ws + 3 * h_btc);   // transposed V: [span][col][t]
    f16* a16  = (f16*)(ws + 4 * h_btc);
    size_t off = 5 * h_btc;
    const size_t wsz = (size_t)E * C * C * sizeof(f16);        // 4,718,592
    f16* Wq16 = (f16*)(ws + off); off += wsz;
    f16* Wk16 = (f16*)(ws + off); off += wsz;
    f16* Wv16 = (f16*)(ws + off); off += wsz;
    f16* Wo16 = (f16*)(ws + off); off += (size_t)C * C * sizeof(f16);
    int*   eidx = (int*)(ws + off); off += 2048;
    float* ewts = (float*)(ws + off); off += 2048;
    float* entp = (float*)(ws + off); off += 1024;
    float* pooled = (float*)(ws + off); off += (size_t)BN * C * sizeof(float);

    cvt_x_pool<<<dim3(BN), dim3(768), 0, stream>>>(x, x16, pooled);
    cvt_w_frag<<<dim3(48, 3), dim3(768), 0, stream>>>(Wq, Wk, Wv,
                                                      Wq16, Wk16, Wv16);
    cvt_wo<<<dim3(288), dim3(256), 0, stream>>>(Wo, Wo16);
    gate_mlp<<<dim3(BN), dim3(128), 0, stream>>>(pooled, gW1, gb1, gW2, gb2,
                                                 eidx, ewts, entp);
    entropy_kernel<<<dim3(1), dim3(256), 0, stream>>>(entp, out + BTC);

    qkv_mfma<<<dim3(BN, 3, 3), dim3(256), 0, stream>>>(x16, Wq16, bq, Wk16, bk, Wv16, bv,
                                                       eidx, ewts, q16, k16, vt16);
    attn_mfma<<<dim3(NH, BN), dim3(256), 0, stream>>>(q16, k16, vt16, a16);
    outproj_mfma<<<dim3(128, 3), dim3(512), 0, stream>>>(a16, Wo16, bo, out);
}